// Round 22
// baseline (41.831 us; speedup 1.0000x reference)
//
#include <hip/hip_runtime.h>
#include <hip/hip_bf16.h>

#define BB 1024
#define DD 256
#define NREL 42
#define AST 264   // bf16 halves/row: 528 B rows -> 16B-aligned b128 gathers

typedef __attribute__((ext_vector_type(8))) short short8_t;
typedef __attribute__((ext_vector_type(4))) short short4_t;
typedef __attribute__((ext_vector_type(2))) short short2_t;
typedef __attribute__((ext_vector_type(4))) float f32x4;
typedef __attribute__((ext_vector_type(2))) float f32x2;
typedef __attribute__((ext_vector_type(4))) int   i32x4;
typedef __attribute__((ext_vector_type(2))) int   i32x2;
typedef __attribute__((ext_vector_type(4))) unsigned int u32x4;

__device__ __forceinline__ unsigned short bf16_of(float f) {
    // round-to-nearest-even f32 -> bf16 (inputs are finite normals)
    unsigned u = __float_as_uint(f);
    return (unsigned short)((u + 0x7FFFu + ((u >> 16) & 1u)) >> 16);
}

__device__ __forceinline__ float blo(unsigned u) { return __uint_as_float(u << 16); }
__device__ __forceinline__ float bhi(unsigned u) { return __uint_as_float(u & 0xFFFF0000u); }

// Two 8-term bf16 dots sharing ONE x operand: x expansion done once.
__device__ __forceinline__ void dot8bf2(u32x4 aa, u32x4 ab, u32x4 xv,
                                        float& ra, float& rb) {
    #pragma unroll
    for (int e = 0; e < 4; ++e) {
        const float xl = blo(xv[e]);
        const float xh = bhi(xv[e]);
        ra = fmaf(blo(aa[e]), xl, ra);
        ra = fmaf(bhi(aa[e]), xh, ra);
        rb = fmaf(blo(ab[e]), xl, rb);
        rb = fmaf(bhi(ab[e]), xh, rb);
    }
}

// ---------------- K0: x -> bf16 interleaved xh8 [d8][j][8] + bf16 transposed xbfT
__global__ __launch_bounds__(256) void cvt_kernel(const float* __restrict__ x,
                                                  unsigned short* __restrict__ xh8,
                                                  unsigned short* __restrict__ xbfT) {
    __shared__ float t32[64][68];
    const int bj = blockIdx.x * 64;
    const int bd = blockIdx.y * 64;
    const int tid = threadIdx.x;
    const int tr = tid >> 4;
    const int tc = tid & 15;

    #pragma unroll
    for (int rr = 0; rr < 4; ++rr) {
        const int jl = rr * 16 + tr;
        const f32x4 v = *reinterpret_cast<const f32x4*>(&x[(bj + jl) * DD + bd + tc * 4]);
        *reinterpret_cast<f32x4*>(&t32[jl][tc * 4]) = v;
    }
    __syncthreads();

    // bf16 transposed copy for the output GEMM
    #pragma unroll
    for (int rr = 0; rr < 4; ++rr) {
        const int dl = rr * 16 + tr;
        short4_t h;
        #pragma unroll
        for (int e = 0; e < 4; ++e) h[e] = (short)bf16_of(t32[tc * 4 + e][dl]);
        *reinterpret_cast<short4_t*>(&xbfT[(bd + dl) * BB + bj + tc * 4]) = h;
    }

    // bf16 interleaved: cell (jl, d8l); 512 cells over 256 threads
    #pragma unroll
    for (int c = 0; c < 2; ++c) {
        const int idx = c * 256 + tid;
        const int jl  = idx & 63;
        const int d8l = idx >> 6;           // 0..7
        short8_t hv;
        #pragma unroll
        for (int e = 0; e < 8; ++e) hv[e] = (short)bf16_of(t32[jl][d8l * 8 + e]);
        *reinterpret_cast<short8_t*>(
            &xh8[(size_t)((bd >> 3) + d8l) * (BB * 8) + (bj + jl) * 8]) = hv;
    }
}

// ---------------- K1 (fused): 2-row bf16 gather-dot + softmax -> normalized P ---
// 512 blocks x 1024 thr; LDS 56.7 KB and target VGPR <= 64 -> 2 blocks/CU =
// 32 waves/CU (HW cap; was 16 in r21 @40.5us). Block = rows {2b, 2b+1}; lane
// owns ONE j x 2 rows (2 accumulators, dot8bf2 shares the x expansion).
// Per d8: 1 coalesced 16B x load + 2 b128 LDS A-gathers + 20 VALU. Softmax is
// slice-parallel (wave = row x 1/8-slice, 2 vals/lane, partials via tiny LDS)
// to keep register pressure ~30 and protect the 64-VGPR occupancy gate.
// Logit arithmetic bit-identical to r17-r21 (bf16 expand + f32 fmaf).
__global__ __launch_bounds__(1024) void attn_kernel(const float* __restrict__ x,
                                                    const int* __restrict__ q,
                                                    const float* __restrict__ R,
                                                    const unsigned short* __restrict__ xh8,
                                                    unsigned short* __restrict__ P) {
    __shared__ __align__(16) unsigned short Ah[2][NREL * AST];   // 44352 B
    __shared__ float s_attn[2][BB];                              // 8192 B
    __shared__ unsigned short s_qs[2][BB];                       // 4096 B
    __shared__ float red_m[2][8], red_s[2][8];

    const int tid  = threadIdx.x;
    const int w    = tid >> 6;       // 0..15
    const int lane = tid & 63;
    const int i0   = blockIdx.x * 2;

    // --- q rows -> LDS (u16): 2 rows x 1024 over 1024 threads, 2 each ---
    {
        const int r  = tid >> 9;            // 0/1
        const int c2 = (tid & 511) * 2;
        const i32x2 qa = *reinterpret_cast<const i32x2*>(&q[(i0 + r) * BB + c2]);
        short2_t sa;
        sa[0] = (short)qa[0]; sa[1] = (short)qa[1];
        *reinterpret_cast<short2_t*>(&s_qs[r][c2]) = sa;
    }

    // --- stage A for 2 rows (bf16): 2 x 42 x 32 chunks of 8 ---
    #pragma unroll
    for (int i2 = 0; i2 < 2; ++i2) {
        const int i = i0 + i2;
        for (int c = tid; c < NREL * 32; c += 1024) {
            const int k  = c >> 5;
            const int d0 = (c & 31) * 8;
            const f32x4 r0 = *reinterpret_cast<const f32x4*>(&R[k * DD + d0]);
            const f32x4 r1 = *reinterpret_cast<const f32x4*>(&R[k * DD + d0 + 4]);
            const f32x4 x0 = *reinterpret_cast<const f32x4*>(&x[i * DD + d0]);
            const f32x4 x1 = *reinterpret_cast<const f32x4*>(&x[i * DD + d0 + 4]);
            short8_t hv;
            #pragma unroll
            for (int e = 0; e < 4; ++e) {
                hv[e]     = (short)bf16_of(r0[e] * x0[e]);
                hv[e + 4] = (short)bf16_of(r1[e] * x1[e]);
            }
            *reinterpret_cast<short8_t*>(&Ah[i2][k * AST + d0]) = hv;   // 16B store
        }
    }

    __syncthreads();

    // --- 1 j-stream x 2 rows per lane ---
    const int j0 = tid;          // 0..1023: this thread's column j
    const unsigned short* a0 = &Ah[0][(int)s_qs[0][j0] * AST];
    const unsigned short* a1 = &Ah[1][(int)s_qs[1][j0] * AST];
    const unsigned short* xp = xh8 + (size_t)j0 * 8;

    float c0 = 0.f, c1 = 0.f;

    #pragma unroll 2
    for (int d8 = 0; d8 < 32; ++d8) {
        const u32x4 xv = *reinterpret_cast<const u32x4*>(xp + (size_t)d8 * (BB * 8));
        const int ao = d8 * 8;
        const u32x4 av0 = *reinterpret_cast<const u32x4*>(a0 + ao);   // ds_read_b128
        const u32x4 av1 = *reinterpret_cast<const u32x4*>(a1 + ao);
        dot8bf2(av0, av1, xv, c0, c1);
    }

    s_attn[0][j0] = c0;
    s_attn[1][j0] = c1;

    __syncthreads();

    // --- softmax, slice-parallel: wave w = (row w>>3, slice w&7), 2 vals/lane ---
    const int r  = w >> 3;       // 0/1
    const int s  = w & 7;        // slice of 128 j's
    const int jb = s * 128 + lane * 2;
    const int i  = i0 + r;

    const f32x2 v = *reinterpret_cast<const f32x2*>(&s_attn[r][jb]);
    float m = fmaxf(v[0], v[1]);
    #pragma unroll
    for (int off = 1; off < 64; off <<= 1) m = fmaxf(m, __shfl_xor(m, off));
    if (lane == 0) red_m[r][s] = m;
    __syncthreads();
    m = red_m[r][0];
    #pragma unroll
    for (int e = 1; e < 8; ++e) m = fmaxf(m, red_m[r][e]);

    const float e0 = __expf(v[0] - m);
    const float e1 = __expf(v[1] - m);
    float ssum = e0 + e1;
    #pragma unroll
    for (int off = 1; off < 64; off <<= 1) ssum += __shfl_xor(ssum, off);
    if (lane == 0) red_s[r][s] = ssum;
    __syncthreads();
    ssum = 0.f;
    #pragma unroll
    for (int e = 1; e < 9; ++e) ssum += red_s[r][e - 1];
    const float inv = 1.0f / ssum;

    {
        short2_t pv;
        pv[0] = (short)bf16_of(e0 * inv);
        pv[1] = (short)bf16_of(e1 * inv);
        *reinterpret_cast<short2_t*>(&P[i * BB + jb]) = pv;
    }
}

// ---------------- K3a: partial out GEMM, split-K z=4 -----------------------------
__global__ __launch_bounds__(256) void out_partial(const unsigned short* __restrict__ P,
                                                   const unsigned short* __restrict__ xbfT,
                                                   float* __restrict__ part) {
    const int tid = threadIdx.x;
    const int wave = tid >> 6, lane = tid & 63;
    const int lcol = lane & 15;
    const int lk8  = (lane >> 4) * 8;
    const int i0 = blockIdx.y * 64 + wave * 16;
    const int d0 = blockIdx.x * 64;
    const int k0 = blockIdx.z * 256;

    f32x4 acc[4];
    #pragma unroll
    for (int nt = 0; nt < 4; ++nt) acc[nt] = (f32x4)0.0f;

    #pragma unroll
    for (int ks = 0; ks < 8; ++ks) {
        const short8_t a = *reinterpret_cast<const short8_t*>(
            &P[(i0 + lcol) * BB + k0 + ks * 32 + lk8]);
        #pragma unroll
        for (int nt = 0; nt < 4; ++nt) {
            const short8_t b = *reinterpret_cast<const short8_t*>(
                &xbfT[(d0 + nt * 16 + lcol) * BB + k0 + ks * 32 + lk8]);
            acc[nt] = __builtin_amdgcn_mfma_f32_16x16x32_bf16(a, b, acc[nt], 0, 0, 0);
        }
    }

    const int rbase = (lane >> 4) * 4;
    float* pz = part + (size_t)blockIdx.z * BB * DD;
    #pragma unroll
    for (int r = 0; r < 4; ++r)
        #pragma unroll
        for (int nt = 0; nt < 4; ++nt)
            pz[(i0 + rbase + r) * DD + d0 + nt * 16 + lcol] = acc[nt][r];
}

// ---------------- K3b: out = sum_z part[z] (P already normalized) ---------------
__global__ __launch_bounds__(256) void out_reduce(const float* __restrict__ part,
                                                  float* __restrict__ out) {
    const int idx = blockIdx.x * DD + threadIdx.x;
    out[idx] = (part[idx] + part[BB * DD + idx]) +
               (part[2 * BB * DD + idx] + part[3 * BB * DD + idx]);
}

// ---------------- launch ---------------------------------------------------------
extern "C" void kernel_launch(void* const* d_in, const int* in_sizes, int n_in,
                              void* d_out, int out_size, void* d_ws, size_t ws_size,
                              hipStream_t stream) {
    (void)in_sizes; (void)n_in; (void)out_size; (void)ws_size;
    const float* x = (const float*)d_in[0];
    // d_in[1] = x_mask (unused), d_in[3] = f (unused)
    const int* q = (const int*)d_in[2];
    const float* R = (const float*)d_in[4];
    float* out = (float*)d_out;

    char* ws = (char*)d_ws;
    unsigned short* xh8  = (unsigned short*)(ws);                  // 512 KB
    unsigned short* xbfT = (unsigned short*)(ws + (512u << 10));   // 512 KB
    unsigned short* P    = (unsigned short*)(ws + (1024u << 10));  // 2 MB
    float*          part = (float*)(ws + (3072u << 10));           // 4 MB (z=4)

    cvt_kernel<<<dim3(16, 4), 256, 0, stream>>>(x, xh8, xbfT);
    attn_kernel<<<dim3(512), 1024, 0, stream>>>(x, q, R, xh8, P);
    out_partial<<<dim3(4, 16, 4), 256, 0, stream>>>(P, xbfT, part);
    out_reduce<<<dim3(BB), 256, 0, stream>>>(part, out);
}

// Round 23
// 40.906 us; speedup vs baseline: 1.0226x; 1.0226x over previous
//
#include <hip/hip_runtime.h>
#include <hip/hip_bf16.h>

#define BB 1024
#define DD 256
#define NREL 42
#define AST 264   // bf16 halves/row: 528 B rows -> 16B-aligned b128 gathers;
                  // row starts spread over 8 bank groups (4k%32) -> near-uniform

typedef __attribute__((ext_vector_type(8))) short short8_t;
typedef __attribute__((ext_vector_type(4))) short short4_t;
typedef __attribute__((ext_vector_type(4))) float f32x4;
typedef __attribute__((ext_vector_type(4))) int   i32x4;
typedef __attribute__((ext_vector_type(4))) unsigned int u32x4;

__device__ __forceinline__ unsigned short bf16_of(float f) {
    // round-to-nearest-even f32 -> bf16 (inputs are finite normals)
    unsigned u = __float_as_uint(f);
    return (unsigned short)((u + 0x7FFFu + ((u >> 16) & 1u)) >> 16);
}

__device__ __forceinline__ float blo(unsigned u) { return __uint_as_float(u << 16); }
__device__ __forceinline__ float bhi(unsigned u) { return __uint_as_float(u & 0xFFFF0000u); }

// Four 8-term bf16 dots sharing ONE x operand: x expansion done once.
__device__ __forceinline__ void dot8bf4(u32x4 a0, u32x4 a1, u32x4 a2, u32x4 a3,
                                        u32x4 xv,
                                        float& r0, float& r1, float& r2, float& r3) {
    #pragma unroll
    for (int e = 0; e < 4; ++e) {
        const float xl = blo(xv[e]);
        const float xh = bhi(xv[e]);
        r0 = fmaf(blo(a0[e]), xl, r0);  r0 = fmaf(bhi(a0[e]), xh, r0);
        r1 = fmaf(blo(a1[e]), xl, r1);  r1 = fmaf(bhi(a1[e]), xh, r1);
        r2 = fmaf(blo(a2[e]), xl, r2);  r2 = fmaf(bhi(a2[e]), xh, r2);
        r3 = fmaf(blo(a3[e]), xl, r3);  r3 = fmaf(bhi(a3[e]), xh, r3);
    }
}

// ---------------- K0: x -> bf16 interleaved xh8 [d8][j][8] + bf16 transposed xbfT
__global__ __launch_bounds__(256) void cvt_kernel(const float* __restrict__ x,
                                                  unsigned short* __restrict__ xh8,
                                                  unsigned short* __restrict__ xbfT) {
    __shared__ float t32[64][68];
    const int bj = blockIdx.x * 64;
    const int bd = blockIdx.y * 64;
    const int tid = threadIdx.x;
    const int tr = tid >> 4;
    const int tc = tid & 15;

    #pragma unroll
    for (int rr = 0; rr < 4; ++rr) {
        const int jl = rr * 16 + tr;
        const f32x4 v = *reinterpret_cast<const f32x4*>(&x[(bj + jl) * DD + bd + tc * 4]);
        *reinterpret_cast<f32x4*>(&t32[jl][tc * 4]) = v;
    }
    __syncthreads();

    // bf16 transposed copy for the output GEMM
    #pragma unroll
    for (int rr = 0; rr < 4; ++rr) {
        const int dl = rr * 16 + tr;
        short4_t h;
        #pragma unroll
        for (int e = 0; e < 4; ++e) h[e] = (short)bf16_of(t32[tc * 4 + e][dl]);
        *reinterpret_cast<short4_t*>(&xbfT[(bd + dl) * BB + bj + tc * 4]) = h;
    }

    // bf16 interleaved: cell (jl, d8l); 512 cells over 256 threads
    #pragma unroll
    for (int c = 0; c < 2; ++c) {
        const int idx = c * 256 + tid;
        const int jl  = idx & 63;
        const int d8l = idx >> 6;           // 0..7
        short8_t hv;
        #pragma unroll
        for (int e = 0; e < 8; ++e) hv[e] = (short)bf16_of(t32[jl][d8l * 8 + e]);
        *reinterpret_cast<short8_t*>(
            &xh8[(size_t)((bd >> 3) + d8l) * (BB * 8) + (bj + jl) * 8]) = hv;
    }
}

// ---------------- K1 (fused): 4-row bf16 gather-dot + softmax -> normalized P ---
// EMPIRICAL OPTIMUM (round 21, 40.5us total). 256 blocks x 1024 thr
// (1 block/CU, 16 waves/CU = 4/SIMD). Block = rows {4b..4b+3}; lane owns
// 1 j-stream x 4 rows (4 accumulators, dot8bf4 shares the x expansion).
// Probed neighbors all regress: 8 waves/CU (r20 42.7), 32 waves/CU via
// 2x1024-thr blocks (r22 41.8), 2-row (r19 43.8), 1-row (r17/18 48.6+),
// MFMA formulation family (r9/r15 52.5). Per d8: 1 coalesced 16B x load +
// 4 b128 LDS A-gathers + dot8bf4 (bf16 expand + f32 fmaf).
__global__ __launch_bounds__(1024) void attn_kernel(const float* __restrict__ x,
                                                    const int* __restrict__ q,
                                                    const float* __restrict__ R,
                                                    const unsigned short* __restrict__ xh8,
                                                    unsigned short* __restrict__ P) {
    __shared__ __align__(16) unsigned short Ah[4][NREL * AST];   // 88704 B
    __shared__ float s_attn[4][BB];                              // 16384 B
    __shared__ unsigned short s_qs[4][BB];                       // 8192 B

    const int tid  = threadIdx.x;
    const int w    = tid >> 6;       // 0..15
    const int lane = tid & 63;
    const int i0   = blockIdx.x * 4;

    // --- q rows -> LDS (u16): 4 rows x 1024 over 1024 threads, 4 each ---
    {
        const int r  = tid >> 8;            // 0..3
        const int c4 = (tid & 255) * 4;
        const int qi = i0 + r;
        const i32x4 qa = *reinterpret_cast<const i32x4*>(&q[qi * BB + c4]);
        short4_t sa;
        sa[0] = (short)qa[0]; sa[1] = (short)qa[1];
        sa[2] = (short)qa[2]; sa[3] = (short)qa[3];
        *reinterpret_cast<short4_t*>(&s_qs[r][c4]) = sa;
    }

    // --- stage A for 4 rows (bf16): 4 x 42 x 32 chunks of 8 ---
    #pragma unroll
    for (int i2 = 0; i2 < 4; ++i2) {
        const int i = i0 + i2;
        for (int c = tid; c < NREL * 32; c += 1024) {
            const int k  = c >> 5;
            const int d0 = (c & 31) * 8;
            const f32x4 r0 = *reinterpret_cast<const f32x4*>(&R[k * DD + d0]);
            const f32x4 r1 = *reinterpret_cast<const f32x4*>(&R[k * DD + d0 + 4]);
            const f32x4 x0 = *reinterpret_cast<const f32x4*>(&x[i * DD + d0]);
            const f32x4 x1 = *reinterpret_cast<const f32x4*>(&x[i * DD + d0 + 4]);
            short8_t hv;
            #pragma unroll
            for (int e = 0; e < 4; ++e) {
                hv[e]     = (short)bf16_of(r0[e] * x0[e]);
                hv[e + 4] = (short)bf16_of(r1[e] * x1[e]);
            }
            *reinterpret_cast<short8_t*>(&Ah[i2][k * AST + d0]) = hv;   // 16B store
        }
    }

    __syncthreads();

    // --- 1 j-stream x 4 rows per lane ---
    const int j0 = tid;          // 0..1023: this thread's column j
    const unsigned short* a0 = &Ah[0][(int)s_qs[0][j0] * AST];
    const unsigned short* a1 = &Ah[1][(int)s_qs[1][j0] * AST];
    const unsigned short* a2 = &Ah[2][(int)s_qs[2][j0] * AST];
    const unsigned short* a3 = &Ah[3][(int)s_qs[3][j0] * AST];
    const unsigned short* xp = xh8 + (size_t)j0 * 8;

    float c0 = 0.f, c1 = 0.f, c2 = 0.f, c3 = 0.f;

    #pragma unroll 2
    for (int d8 = 0; d8 < 32; ++d8) {
        const u32x4 xv = *reinterpret_cast<const u32x4*>(xp + (size_t)d8 * (BB * 8));

        const int ao = d8 * 8;
        const u32x4 av0 = *reinterpret_cast<const u32x4*>(a0 + ao);   // ds_read_b128
        const u32x4 av1 = *reinterpret_cast<const u32x4*>(a1 + ao);
        const u32x4 av2 = *reinterpret_cast<const u32x4*>(a2 + ao);
        const u32x4 av3 = *reinterpret_cast<const u32x4*>(a3 + ao);

        dot8bf4(av0, av1, av2, av3, xv, c0, c1, c2, c3);
    }

    s_attn[0][j0] = c0;
    s_attn[1][j0] = c1;
    s_attn[2][j0] = c2;
    s_attn[3][j0] = c3;

    __syncthreads();

    // --- softmax: wave w reduces row (w>>2) fully, writes quarter (w&3) of P ---
    const int p2 = w >> 2;       // row 0..3
    const int jq = w & 3;        // quarter 0..3
    const int i  = i0 + p2;

    f32x4 v4[4];
    #pragma unroll
    for (int kk = 0; kk < 4; ++kk)
        v4[kk] = *reinterpret_cast<const f32x4*>(&s_attn[p2][kk * 256 + lane * 4]);

    float m = -1e30f;
    #pragma unroll
    for (int kk = 0; kk < 4; ++kk)
        m = fmaxf(m, fmaxf(fmaxf(v4[kk][0], v4[kk][1]), fmaxf(v4[kk][2], v4[kk][3])));
    #pragma unroll
    for (int off = 1; off < 64; off <<= 1) m = fmaxf(m, __shfl_xor(m, off));

    float e[16];
    float ssum = 0.f;
    #pragma unroll
    for (int kk = 0; kk < 4; ++kk)
        #pragma unroll
        for (int ee = 0; ee < 4; ++ee) {
            const float t2 = __expf(v4[kk][ee] - m);
            e[kk * 4 + ee] = t2;
            ssum += t2;
        }
    #pragma unroll
    for (int off = 1; off < 64; off <<= 1) ssum += __shfl_xor(ssum, off);
    const float inv = 1.0f / ssum;

    {
        short4_t pv;
        #pragma unroll
        for (int ee = 0; ee < 4; ++ee) pv[ee] = (short)bf16_of(e[jq * 4 + ee] * inv);
        *reinterpret_cast<short4_t*>(&P[i * BB + jq * 256 + lane * 4]) = pv;
    }
}

// ---------------- K3a: partial out GEMM, split-K z=4 -----------------------------
__global__ __launch_bounds__(256) void out_partial(const unsigned short* __restrict__ P,
                                                   const unsigned short* __restrict__ xbfT,
                                                   float* __restrict__ part) {
    const int tid = threadIdx.x;
    const int wave = tid >> 6, lane = tid & 63;
    const int lcol = lane & 15;
    const int lk8  = (lane >> 4) * 8;
    const int i0 = blockIdx.y * 64 + wave * 16;
    const int d0 = blockIdx.x * 64;
    const int k0 = blockIdx.z * 256;

    f32x4 acc[4];
    #pragma unroll
    for (int nt = 0; nt < 4; ++nt) acc[nt] = (f32x4)0.0f;

    #pragma unroll
    for (int ks = 0; ks < 8; ++ks) {
        const short8_t a = *reinterpret_cast<const short8_t*>(
            &P[(i0 + lcol) * BB + k0 + ks * 32 + lk8]);
        #pragma unroll
        for (int nt = 0; nt < 4; ++nt) {
            const short8_t b = *reinterpret_cast<const short8_t*>(
                &xbfT[(d0 + nt * 16 + lcol) * BB + k0 + ks * 32 + lk8]);
            acc[nt] = __builtin_amdgcn_mfma_f32_16x16x32_bf16(a, b, acc[nt], 0, 0, 0);
        }
    }

    const int rbase = (lane >> 4) * 4;
    float* pz = part + (size_t)blockIdx.z * BB * DD;
    #pragma unroll
    for (int r = 0; r < 4; ++r)
        #pragma unroll
        for (int nt = 0; nt < 4; ++nt)
            pz[(i0 + rbase + r) * DD + d0 + nt * 16 + lcol] = acc[nt][r];
}

// ---------------- K3b: out = sum_z part[z] (P already normalized) ---------------
__global__ __launch_bounds__(256) void out_reduce(const float* __restrict__ part,
                                                  float* __restrict__ out) {
    const int idx = blockIdx.x * DD + threadIdx.x;
    out[idx] = (part[idx] + part[BB * DD + idx]) +
               (part[2 * BB * DD + idx] + part[3 * BB * DD + idx]);
}

// ---------------- launch ---------------------------------------------------------
extern "C" void kernel_launch(void* const* d_in, const int* in_sizes, int n_in,
                              void* d_out, int out_size, void* d_ws, size_t ws_size,
                              hipStream_t stream) {
    (void)in_sizes; (void)n_in; (void)out_size; (void)ws_size;
    const float* x = (const float*)d_in[0];
    // d_in[1] = x_mask (unused), d_in[3] = f (unused)
    const int* q = (const int*)d_in[2];
    const float* R = (const float*)d_in[4];
    float* out = (float*)d_out;

    char* ws = (char*)d_ws;
    unsigned short* xh8  = (unsigned short*)(ws);                  // 512 KB
    unsigned short* xbfT = (unsigned short*)(ws + (512u << 10));   // 512 KB
    unsigned short* P    = (unsigned short*)(ws + (1024u << 10));  // 2 MB
    float*          part = (float*)(ws + (3072u << 10));           // 4 MB (z=4)

    cvt_kernel<<<dim3(16, 4), 256, 0, stream>>>(x, xh8, xbfT);
    attn_kernel<<<dim3(256), 1024, 0, stream>>>(x, q, R, xh8, P);
    out_partial<<<dim3(4, 16, 4), 256, 0, stream>>>(P, xbfT, part);
    out_reduce<<<dim3(BB), 256, 0, stream>>>(part, out);
}